// Round 6
// baseline (379.633 us; speedup 1.0000x reference)
//
#include <hip/hip_runtime.h>
#include <hip/hip_bf16.h>

#define B_ 64
#define L_ 512
#define H_ 1024
#define A_ 1024

typedef short bf16x8 __attribute__((ext_vector_type(8)));
typedef float f32x4 __attribute__((ext_vector_type(4)));

__device__ __forceinline__ void gld16(const void* g, void* l) {
  __builtin_amdgcn_global_load_lds((const __attribute__((address_space(1))) void*)g,
                                   (__attribute__((address_space(3))) void*)l, 16, 0, 0);
}

// f32 -> bf16 RNE bit trick (cold paths)
__device__ __forceinline__ unsigned short f2bf(float f) {
  unsigned u = __builtin_bit_cast(unsigned, f);
  u = (u + 0x7fffu + ((u >> 16) & 1u)) >> 16;
  return (unsigned short)u;
}

// hot-path cast: compiler fuses pairs into v_cvt_pk_bf16_f32
__device__ __forceinline__ unsigned short cvtbf(float f) {
  __hip_bfloat16 b = __float2bfloat16(f);
  return __builtin_bit_cast(unsigned short, b);
}

// tanh(x) = 1 - 2/(exp(2x)+1) with fast rcp (~1ulp, invisible in bf16)
__device__ __forceinline__ float fast_tanh(float x) {
  float e = __expf(2.f * x);
  float r = __builtin_amdgcn_rcpf(e + 1.f);
  return __builtin_fmaf(-2.f, r, 1.f);
}

// ---------- K0: Wt[a][h] = bf16(W[h][a]) ----------
__global__ __launch_bounds__(256) void wtrans_kernel(const float* __restrict__ W,
                                                     unsigned short* __restrict__ Wt) {
  __shared__ float tile[32][33];
  int tx = threadIdx.x & 31, ty = threadIdx.x >> 5;  // 32 x 8
  int a0 = (blockIdx.x & 31) << 5, h0 = (blockIdx.x >> 5) << 5;
#pragma unroll
  for (int i = 0; i < 4; ++i) {
    int h = ty + i * 8;
    tile[h][tx] = W[(size_t)(h0 + h) * A_ + a0 + tx];
  }
  __syncthreads();
#pragma unroll
  for (int i = 0; i < 4; ++i) {
    int a = ty + i * 8;
    Wt[(size_t)(a0 + a) * H_ + h0 + tx] = f2bf(tile[tx][a]);
  }
}

// ---------- K1: fused 256x256 proj: Pb = bf16(tanh(X_f32 @ Wt^T)[*diag]) ----------
// 512 threads = 8 waves (2Mx4N). BK=64, dbuf LDS 128KB.
// A: f32 global->regs issued at tile start (T14), cvt_pk + swizzled ds_write
//    AFTER the MFMA block; compiler's own vmcnt wait covers the a-regs.
// B: global_load_lds (pre-swizzled source), drained by vmcnt(0) at tile end
//    (issued one full tile earlier; Wt is 2MB -> L2-resident).
// ONE raw s_barrier per K-tile: staging into nb begins only after the barrier
// that ends the previous tile, whose readers of nb finished before reaching it.
__global__ __launch_bounds__(512, 2) void proj8_kernel(
    const float* __restrict__ Xlt, const float* __restrict__ Xrt,
    const unsigned short* __restrict__ Wt, const float* __restrict__ diag,
    unsigned short* __restrict__ Pb) {
  __shared__ unsigned short As[2][256 * 64];  // 2 x 32 KB
  __shared__ unsigned short Bs[2][256 * 64];  // 2 x 32 KB
  int t = threadIdx.x;                 // 0..511
  int lane = t & 63, wave = t >> 6;
  int wr = wave >> 2, wcn = wave & 3;  // wave grid 2M x 4N, each 128x64 out
  int l15 = lane & 15, l4 = lane >> 4;

  // XCD swizzle: each XCD runs 4 consecutive N-tiles of one M-tile
  int bid = (int)blockIdx.x;           // 1024 blocks
  int x = bid & 7, k = bid >> 3;       // k in [0,128)
  int mt = x + 8 * (k >> 2);           // [0,256)
  int nt = k & 3;                      // [0,4)
  int mrow0 = mt << 8;
  int ncol0 = nt << 8;
  int isLt = (mt < 128);
  const float* X = isLt ? Xlt : Xrt;
  int xrow0 = (isLt ? mt : mt - 128) << 8;

  // A reg-staging: thread covers row ra = t>>1, k-half kh = t&1 (32 floats)
  int ra = t >> 1, kh = t & 1;
  const float* Asrc = X + (size_t)(xrow0 + ra) * H_ + kh * 32;
  // ds_write targets: chunk c=0..3 -> global chunk j=kh*4+c at slot j^(ra&7)
  int awoff[4];
#pragma unroll
  for (int c = 0; c < 4; ++c)
    awoff[c] = (ra * 8 + ((kh * 4 + c) ^ (ra & 7))) * 8;

  // B staging via gld16: thread covers rows r0+{0,64,128,192}, chunk t&7, src pre-swizzled
  int r0 = t >> 3;
  int swzc = ((t & 7) ^ (r0 & 7)) << 3;
  const unsigned short* B0 = Wt + (size_t)(ncol0 + r0) * H_ + swzc;

  f32x4 acc[8][4] = {};
  int rdsw0 = (l4 ^ (l15 & 7)) * 8;        // kslice0 read swizzle
  int rdsw1 = ((4 + l4) ^ (l15 & 7)) * 8;  // kslice1

  float4 a0[8];

#define CVT_WRITE(buf)                                                     \
  {                                                                        \
    _Pragma("unroll") for (int c = 0; c < 4; ++c) {                        \
      bf16x8 v;                                                            \
      v[0] = (short)cvtbf(a0[2 * c].x); v[1] = (short)cvtbf(a0[2 * c].y);  \
      v[2] = (short)cvtbf(a0[2 * c].z); v[3] = (short)cvtbf(a0[2 * c].w);  \
      v[4] = (short)cvtbf(a0[2 * c + 1].x); v[5] = (short)cvtbf(a0[2 * c + 1].y); \
      v[6] = (short)cvtbf(a0[2 * c + 1].z); v[7] = (short)cvtbf(a0[2 * c + 1].w); \
      *(bf16x8*)&As[buf][awoff[c]] = v;                                    \
    }                                                                      \
  }

  // ---- prologue: stage tile 0 into buf 0 ----
#pragma unroll
  for (int j = 0; j < 8; ++j) a0[j] = ((const float4*)Asrc)[j];
#pragma unroll
  for (int i = 0; i < 4; ++i)
    gld16(B0 + (size_t)i * 64 * H_, &Bs[0][(i * 512 + t) * 8]);
  CVT_WRITE(0);
  asm volatile("s_waitcnt vmcnt(0) lgkmcnt(0)" ::: "memory");
  asm volatile("s_barrier" ::: "memory");

  int cur = 0;
  for (int kt = 0; kt < 16; ++kt) {
    bool more = (kt < 15);
    int nk = (kt + 1) * 64;
    // issue next tile's A loads FIRST (reg), then B gld16 (LDS nb)
    if (more) {
#pragma unroll
      for (int j = 0; j < 8; ++j) a0[j] = ((const float4*)(Asrc + nk))[j];
#pragma unroll
      for (int i = 0; i < 4; ++i)
        gld16(B0 + (size_t)i * 64 * H_ + nk, &Bs[cur ^ 1][(i * 512 + t) * 8]);
    }

    // ---- compute on buf[cur] ----
    const unsigned short* Ac = As[cur];
    const unsigned short* Bc = Bs[cur];
    bf16x8 bq[4][2];
#pragma unroll
    for (int ni = 0; ni < 4; ++ni) {
      int brow = wcn * 64 + ni * 16 + l15;
      bq[ni][0] = *(const bf16x8*)&Bc[brow * 64 + rdsw0];
      bq[ni][1] = *(const bf16x8*)&Bc[brow * 64 + rdsw1];
    }
#pragma unroll
    for (int ph = 0; ph < 4; ++ph) {
      bf16x8 aq[2][2];
#pragma unroll
      for (int m2 = 0; m2 < 2; ++m2) {
        int arow = wr * 128 + (ph * 2 + m2) * 16 + l15;
        aq[m2][0] = *(const bf16x8*)&Ac[arow * 64 + rdsw0];
        aq[m2][1] = *(const bf16x8*)&Ac[arow * 64 + rdsw1];
      }
      __builtin_amdgcn_s_setprio(1);
#pragma unroll
      for (int m2 = 0; m2 < 2; ++m2)
#pragma unroll
        for (int ni = 0; ni < 4; ++ni) {
          acc[ph * 2 + m2][ni] = __builtin_amdgcn_mfma_f32_16x16x32_bf16(
              aq[m2][0], bq[ni][0], acc[ph * 2 + m2][ni], 0, 0, 0);
          acc[ph * 2 + m2][ni] = __builtin_amdgcn_mfma_f32_16x16x32_bf16(
              aq[m2][1], bq[ni][1], acc[ph * 2 + m2][ni], 0, 0, 0);
        }
      __builtin_amdgcn_s_setprio(0);
    }

    // write-late: cvt next tile's A into nb (compiler waits the a-regs)
    if (more) CVT_WRITE(cur ^ 1);
    // drain B gld16 (issued one full tile ago) + ds_writes, then barrier
    asm volatile("s_waitcnt vmcnt(0) lgkmcnt(0)" ::: "memory");
    asm volatile("s_barrier" ::: "memory");
    cur ^= 1;
  }
#undef CVT_WRITE

#pragma unroll
  for (int mi = 0; mi < 8; ++mi) {
#pragma unroll
    for (int ni = 0; ni < 4; ++ni) {
      int col = ncol0 + wcn * 64 + ni * 16 + l15;
      float d = isLt ? diag[col] : 1.0f;
#pragma unroll
      for (int rr = 0; rr < 4; ++rr) {
        int row = mrow0 + wr * 128 + mi * 16 + l4 * 4 + rr;
        Pb[(size_t)row * A_ + col] = f2bf(fast_tanh(acc[mi][ni][rr]) * d);
      }
    }
  }
}

// ---------- K2: scores[b][l][r] = (Plt[b,l,:] . Prt[b,r,:]) * ml * mr ----------
__global__ __launch_bounds__(256) void score_kernel(
    const unsigned short* __restrict__ Plt, const unsigned short* __restrict__ Prt,
    const float* __restrict__ mask_lt, const float* __restrict__ mask_rt,
    float* __restrict__ out) {
  __shared__ unsigned short As[128 * 64];
  __shared__ unsigned short Bs[128 * 64];
  int t = threadIdx.x;
  int lane = t & 63, wave = t >> 6;
  int wr = wave >> 1, wc = wave & 1;
  int l15 = lane & 15, l4 = lane >> 4;

  int bid = (int)blockIdx.x;                 // 1024 blocks
  int x = bid & 7, k = bid >> 3;             // k in [0,128)
  int atile = x + 8 * (k >> 2);              // [0,256)
  int b = atile >> 2, tm = atile & 3, tn = k & 3;

  const unsigned short* Abase = Plt + (size_t)b * L_ * A_ + (size_t)(tm * 128) * A_;
  const unsigned short* Bbase = Prt + (size_t)b * L_ * A_ + (size_t)(tn * 128) * A_;

  const unsigned short* asrc[4];
  const unsigned short* bsrc[4];
  int dst[4];
#pragma unroll
  for (int i = 0; i < 4; ++i) {
    int c = i * 256 + t;
    int r = c >> 3, kc = c & 7;
    int sc = (kc ^ (r & 7)) * 8;
    asrc[i] = &Abase[(size_t)r * A_ + sc];
    bsrc[i] = &Bbase[(size_t)r * A_ + sc];
    dst[i] = c * 8;
  }
  int swz0 = ((0 * 4 + l4) ^ (l15 & 7)) * 8;
  int swz1 = ((1 * 4 + l4) ^ (l15 & 7)) * 8;

  f32x4 acc[4][4] = {};
  for (int kt = 0; kt < A_ / 64; ++kt) {
    int k0 = kt * 64;
    __syncthreads();
#pragma unroll
    for (int i = 0; i < 4; ++i) {
      gld16(asrc[i] + k0, &As[dst[i]]);
      gld16(bsrc[i] + k0, &Bs[dst[i]]);
    }
    __syncthreads();
#pragma unroll
    for (int kk = 0; kk < 2; ++kk) {
      int sw = kk ? swz1 : swz0;
      bf16x8 aq[4], bq[4];
#pragma unroll
      for (int mi = 0; mi < 4; ++mi)
        aq[mi] = *(const bf16x8*)&As[(wr * 64 + mi * 16 + l15) * 64 + sw];
#pragma unroll
      for (int ni = 0; ni < 4; ++ni)
        bq[ni] = *(const bf16x8*)&Bs[(wc * 64 + ni * 16 + l15) * 64 + sw];
#pragma unroll
      for (int mi = 0; mi < 4; ++mi)
#pragma unroll
        for (int ni = 0; ni < 4; ++ni)
          acc[mi][ni] = __builtin_amdgcn_mfma_f32_16x16x32_bf16(aq[mi], bq[ni], acc[mi][ni], 0, 0, 0);
    }
  }
  const float* mlp = mask_lt + b * L_;
  const float* mrp = mask_rt + b * L_;
  float* obase = out + (size_t)b * L_ * L_;
#pragma unroll
  for (int mi = 0; mi < 4; ++mi) {
#pragma unroll
    for (int ni = 0; ni < 4; ++ni) {
      int col = tn * 128 + wc * 64 + ni * 16 + l15;
      float mr = mrp[col];
#pragma unroll
      for (int r = 0; r < 4; ++r) {
        int row = tm * 128 + wr * 64 + mi * 16 + l4 * 4 + r;
        obase[(size_t)row * L_ + col] = acc[mi][ni][r] * mlp[row] * mr;
      }
    }
  }
}

// ---------- K3: in-place row softmax over 512, then re-mask ----------
__global__ __launch_bounds__(256) void softmax_kernel(float* __restrict__ out,
                                                      const float* __restrict__ mask_lt,
                                                      const float* __restrict__ mask_rt) {
  int lane = threadIdx.x & 63, wave = threadIdx.x >> 6;
  int row = (int)blockIdx.x * 4 + wave;  // 0..32767
  int b = row >> 9;
  float* p = out + (size_t)row * L_;
  float4 v0 = *(const float4*)(p + lane * 8);
  float4 v1 = *(const float4*)(p + lane * 8 + 4);
  float m = fmaxf(fmaxf(fmaxf(v0.x, v0.y), fmaxf(v0.z, v0.w)),
                  fmaxf(fmaxf(v1.x, v1.y), fmaxf(v1.z, v1.w)));
#pragma unroll
  for (int off = 32; off; off >>= 1) m = fmaxf(m, __shfl_xor(m, off));
  float e0 = __expf(v0.x - m), e1 = __expf(v0.y - m), e2 = __expf(v0.z - m), e3 = __expf(v0.w - m);
  float e4 = __expf(v1.x - m), e5 = __expf(v1.y - m), e6 = __expf(v1.z - m), e7 = __expf(v1.w - m);
  float s = ((e0 + e1) + (e2 + e3)) + ((e4 + e5) + (e6 + e7));
#pragma unroll
  for (int off = 32; off; off >>= 1) s += __shfl_xor(s, off);
  float sc = (1.0f / s) * mask_lt[row];
  const float* mrp = mask_rt + (b << 9) + lane * 8;
  float4 mr0 = *(const float4*)mrp;
  float4 mr1 = *(const float4*)(mrp + 4);
  float4 o0 = make_float4(e0 * sc * mr0.x, e1 * sc * mr0.y, e2 * sc * mr0.z, e3 * sc * mr0.w);
  float4 o1 = make_float4(e4 * sc * mr1.x, e5 * sc * mr1.y, e6 * sc * mr1.z, e7 * sc * mr1.w);
  *(float4*)(p + lane * 8) = o0;
  *(float4*)(p + lane * 8 + 4) = o1;
}

extern "C" void kernel_launch(void* const* d_in, const int* in_sizes, int n_in,
                              void* d_out, int out_size, void* d_ws, size_t ws_size,
                              hipStream_t stream) {
  const float* reps_lt = (const float*)d_in[0];
  const float* reps_rt = (const float*)d_in[1];
  const float* mask_lt = (const float*)d_in[2];
  const float* mask_rt = (const float*)d_in[3];
  const float* attn_w1 = (const float*)d_in[4];
  const float* diag    = (const float*)d_in[5];
  float* out = (float*)d_out;

  unsigned short* wt  = (unsigned short*)d_ws;       // 2 MB
  unsigned short* pb  = wt + (size_t)H_ * A_;        // 128 MB
  unsigned short* plt = pb;
  unsigned short* prt = pb + (size_t)B_ * L_ * A_;

  hipLaunchKernelGGL(wtrans_kernel, dim3(1024), dim3(256), 0, stream, attn_w1, wt);
  hipLaunchKernelGGL(proj8_kernel, dim3(1024), dim3(512), 0, stream,
                     reps_lt, reps_rt, wt, diag, pb);
  hipLaunchKernelGGL(score_kernel, dim3(1024), dim3(256), 0, stream,
                     plt, prt, mask_lt, mask_rt, out);
  hipLaunchKernelGGL(softmax_kernel, dim3(8192), dim3(256), 0, stream,
                     out, mask_lt, mask_rt);
}

// Round 7
// 364.514 us; speedup vs baseline: 1.0415x; 1.0415x over previous
//
#include <hip/hip_runtime.h>
#include <hip/hip_bf16.h>

#define B_ 64
#define L_ 512
#define H_ 1024
#define A_ 1024

typedef short bf16x8 __attribute__((ext_vector_type(8)));
typedef float f32x4 __attribute__((ext_vector_type(4)));

__device__ __forceinline__ void gld16(const void* g, void* l) {
  __builtin_amdgcn_global_load_lds((const __attribute__((address_space(1))) void*)g,
                                   (__attribute__((address_space(3))) void*)l, 16, 0, 0);
}

// f32 -> bf16 RNE bit trick (cold paths)
__device__ __forceinline__ unsigned short f2bf(float f) {
  unsigned u = __builtin_bit_cast(unsigned, f);
  u = (u + 0x7fffu + ((u >> 16) & 1u)) >> 16;
  return (unsigned short)u;
}

// hot-path cast: compiler fuses pairs into v_cvt_pk_bf16_f32
__device__ __forceinline__ unsigned short cvtbf(float f) {
  __hip_bfloat16 b = __float2bfloat16(f);
  return __builtin_bit_cast(unsigned short, b);
}

// tanh(x) = 1 - 2/(exp(2x)+1) with fast rcp (~1ulp, invisible in bf16)
__device__ __forceinline__ float fast_tanh(float x) {
  float e = __expf(2.f * x);
  float r = __builtin_amdgcn_rcpf(e + 1.f);
  return __builtin_fmaf(-2.f, r, 1.f);
}

// ---------- K-1: Xb = bf16(concat(Xlt, Xrt)), streaming ----------
__global__ __launch_bounds__(256) void cvt_kernel(const float* __restrict__ lt,
                                                  const float* __restrict__ rt,
                                                  unsigned short* __restrict__ xb) {
  const size_t NC = (size_t)B_ * L_ * H_ / 8;  // chunks per tensor
  size_t stride = (size_t)gridDim.x * blockDim.x;
  for (size_t c = (size_t)blockIdx.x * blockDim.x + threadIdx.x; c < 2 * NC; c += stride) {
    const float* src = (c < NC) ? (lt + c * 8) : (rt + (c - NC) * 8);
    float4 v0 = ((const float4*)src)[0];
    float4 v1 = ((const float4*)src)[1];
    bf16x8 o;
    o[0] = (short)cvtbf(v0.x); o[1] = (short)cvtbf(v0.y);
    o[2] = (short)cvtbf(v0.z); o[3] = (short)cvtbf(v0.w);
    o[4] = (short)cvtbf(v1.x); o[5] = (short)cvtbf(v1.y);
    o[6] = (short)cvtbf(v1.z); o[7] = (short)cvtbf(v1.w);
    *(bf16x8*)(xb + c * 8) = o;
  }
}

// ---------- K0: Wt[a][h] = bf16(W[h][a]) ----------
__global__ __launch_bounds__(256) void wtrans_kernel(const float* __restrict__ W,
                                                     unsigned short* __restrict__ Wt) {
  __shared__ float tile[32][33];
  int tx = threadIdx.x & 31, ty = threadIdx.x >> 5;  // 32 x 8
  int a0 = (blockIdx.x & 31) << 5, h0 = (blockIdx.x >> 5) << 5;
#pragma unroll
  for (int i = 0; i < 4; ++i) {
    int h = ty + i * 8;
    tile[h][tx] = W[(size_t)(h0 + h) * A_ + a0 + tx];
  }
  __syncthreads();
#pragma unroll
  for (int i = 0; i < 4; ++i) {
    int a = ty + i * 8;
    Wt[(size_t)(a0 + a) * H_ + h0 + tx] = f2bf(tile[tx][a]);
  }
}

// ---------- K1: 256x256 quad-buffered proj: Pb = bf16(tanh(Xb@Wt^T)[*diag]) ----------
// 512 threads = 8 waves (2Mx4N). BK=32, FOUR LDS buffers (prefetch depth 3):
// at tile j the vmcnt(8) waits only for loads issued 3 compute-phases ago
// (~1400cyc >= L3/HBM latency). One raw s_barrier per tile; stage(j+3) after
// the barrier targets buf[(j-1)&3] whose readers finished before the barrier.
// Chunk swizzle: row r chunk c stored at slot c ^ (r&3) ^ ((r>>2)&3)
// (pre-swizzled global source, linear LDS dest; 2-way max on reads = free).
__global__ __launch_bounds__(512, 2) void proj8_kernel(
    const unsigned short* __restrict__ Xb, const unsigned short* __restrict__ Wt,
    const float* __restrict__ diag, unsigned short* __restrict__ Pb) {
  __shared__ unsigned short As4[4][256 * 32];  // 4 x 16 KB
  __shared__ unsigned short Bs4[4][256 * 32];  // 4 x 16 KB
  int t = threadIdx.x;                 // 0..511
  int lane = t & 63, wave = t >> 6;
  int wr = wave >> 2, wcn = wave & 3;  // wave grid 2M x 4N, each 128x64 out
  int l15 = lane & 15, l4 = lane >> 4;

  // XCD swizzle: each XCD runs 4 consecutive N-tiles of one M-tile
  int bid = (int)blockIdx.x;           // 1024 blocks
  int x = bid & 7, k = bid >> 3;       // k in [0,128)
  int mt = x + 8 * (k >> 2);           // [0,256)
  int nt = k & 3;                      // [0,4)
  int mrow0 = mt << 8;
  int ncol0 = nt << 8;
  int isLt = (mt < 128);

  // staging: issue i covers chunk ci = i*512 + t -> row = ci>>2, chunk c = ci&3
  const unsigned short* asrc[2];
  const unsigned short* bsrc[2];
#pragma unroll
  for (int i = 0; i < 2; ++i) {
    int ci = i * 512 + t;
    int r = ci >> 2, c = ci & 3;
    int sc = (c ^ ((r & 3) ^ ((r >> 2) & 3))) << 3;  // pre-swizzled source chunk
    asrc[i] = Xb + (size_t)(mrow0 + r) * H_ + sc;
    bsrc[i] = Wt + (size_t)(ncol0 + r) * H_ + sc;
  }

#define STAGE4(buf, kt_)                                        \
  {                                                             \
    int ko = (kt_) * 32;                                        \
    gld16(asrc[0] + ko, &As4[buf][t * 8]);                      \
    gld16(asrc[1] + ko, &As4[buf][(512 + t) * 8]);              \
    gld16(bsrc[0] + ko, &Bs4[buf][t * 8]);                      \
    gld16(bsrc[1] + ko, &Bs4[buf][(512 + t) * 8]);              \
  }

  f32x4 acc[8][4] = {};
  // fragment-read swizzle: row == l15 (mod 16); slot = l4 ^ (r&3) ^ ((r>>2)&3)
  int rdsw = (l4 ^ ((l15 & 3) ^ ((l15 >> 2) & 3))) * 8;

  // prologue: 3 tiles in flight
  STAGE4(0, 0);
  STAGE4(1, 1);
  STAGE4(2, 2);

  for (int j = 0; j < 32; ++j) {
    if (j < 30)
      asm volatile("s_waitcnt vmcnt(8)" ::: "memory");
    else if (j == 30)
      asm volatile("s_waitcnt vmcnt(4)" ::: "memory");
    else
      asm volatile("s_waitcnt vmcnt(0)" ::: "memory");
    asm volatile("s_barrier" ::: "memory");
    if (j <= 28) STAGE4((j + 3) & 3, j + 3);

    const unsigned short* Ac = As4[j & 3];
    const unsigned short* Bc = Bs4[j & 3];
    bf16x8 bq[4];
#pragma unroll
    for (int ni = 0; ni < 4; ++ni)
      bq[ni] = *(const bf16x8*)&Bc[(wcn * 64 + ni * 16 + l15) * 32 + rdsw];
#pragma unroll
    for (int ph = 0; ph < 4; ++ph) {
      bf16x8 aq0 = *(const bf16x8*)&Ac[(wr * 128 + (ph * 2) * 16 + l15) * 32 + rdsw];
      bf16x8 aq1 = *(const bf16x8*)&Ac[(wr * 128 + (ph * 2 + 1) * 16 + l15) * 32 + rdsw];
      __builtin_amdgcn_s_setprio(1);
#pragma unroll
      for (int ni = 0; ni < 4; ++ni) {
        acc[ph * 2][ni] = __builtin_amdgcn_mfma_f32_16x16x32_bf16(
            aq0, bq[ni], acc[ph * 2][ni], 0, 0, 0);
        acc[ph * 2 + 1][ni] = __builtin_amdgcn_mfma_f32_16x16x32_bf16(
            aq1, bq[ni], acc[ph * 2 + 1][ni], 0, 0, 0);
      }
      __builtin_amdgcn_s_setprio(0);
    }
  }
#undef STAGE4

#pragma unroll
  for (int mi = 0; mi < 8; ++mi) {
#pragma unroll
    for (int ni = 0; ni < 4; ++ni) {
      int col = ncol0 + wcn * 64 + ni * 16 + l15;
      float d = isLt ? diag[col] : 1.0f;
#pragma unroll
      for (int rr = 0; rr < 4; ++rr) {
        int row = mrow0 + wr * 128 + mi * 16 + l4 * 4 + rr;
        Pb[(size_t)row * A_ + col] = f2bf(fast_tanh(acc[mi][ni][rr]) * d);
      }
    }
  }
}

// ---------- K2: scores[b][l][r] = (Plt[b,l,:] . Prt[b,r,:]) * ml * mr ----------
__global__ __launch_bounds__(256) void score_kernel(
    const unsigned short* __restrict__ Plt, const unsigned short* __restrict__ Prt,
    const float* __restrict__ mask_lt, const float* __restrict__ mask_rt,
    float* __restrict__ out) {
  __shared__ unsigned short As[128 * 64];
  __shared__ unsigned short Bs[128 * 64];
  int t = threadIdx.x;
  int lane = t & 63, wave = t >> 6;
  int wr = wave >> 1, wc = wave & 1;
  int l15 = lane & 15, l4 = lane >> 4;

  int bid = (int)blockIdx.x;                 // 1024 blocks
  int x = bid & 7, k = bid >> 3;             // k in [0,128)
  int atile = x + 8 * (k >> 2);              // [0,256)
  int b = atile >> 2, tm = atile & 3, tn = k & 3;

  const unsigned short* Abase = Plt + (size_t)b * L_ * A_ + (size_t)(tm * 128) * A_;
  const unsigned short* Bbase = Prt + (size_t)b * L_ * A_ + (size_t)(tn * 128) * A_;

  const unsigned short* asrc[4];
  const unsigned short* bsrc[4];
  int dst[4];
#pragma unroll
  for (int i = 0; i < 4; ++i) {
    int c = i * 256 + t;
    int r = c >> 3, kc = c & 7;
    int sc = (kc ^ (r & 7)) * 8;
    asrc[i] = &Abase[(size_t)r * A_ + sc];
    bsrc[i] = &Bbase[(size_t)r * A_ + sc];
    dst[i] = c * 8;
  }
  int swz0 = ((0 * 4 + l4) ^ (l15 & 7)) * 8;
  int swz1 = ((1 * 4 + l4) ^ (l15 & 7)) * 8;

  f32x4 acc[4][4] = {};
  for (int kt = 0; kt < A_ / 64; ++kt) {
    int k0 = kt * 64;
    __syncthreads();
#pragma unroll
    for (int i = 0; i < 4; ++i) {
      gld16(asrc[i] + k0, &As[dst[i]]);
      gld16(bsrc[i] + k0, &Bs[dst[i]]);
    }
    __syncthreads();
#pragma unroll
    for (int kk = 0; kk < 2; ++kk) {
      int sw = kk ? swz1 : swz0;
      bf16x8 aq[4], bq[4];
#pragma unroll
      for (int mi = 0; mi < 4; ++mi)
        aq[mi] = *(const bf16x8*)&As[(wr * 64 + mi * 16 + l15) * 64 + sw];
#pragma unroll
      for (int ni = 0; ni < 4; ++ni)
        bq[ni] = *(const bf16x8*)&Bs[(wc * 64 + ni * 16 + l15) * 64 + sw];
#pragma unroll
      for (int mi = 0; mi < 4; ++mi)
#pragma unroll
        for (int ni = 0; ni < 4; ++ni)
          acc[mi][ni] = __builtin_amdgcn_mfma_f32_16x16x32_bf16(aq[mi], bq[ni], acc[mi][ni], 0, 0, 0);
    }
  }
  const float* mlp = mask_lt + b * L_;
  const float* mrp = mask_rt + b * L_;
  float* obase = out + (size_t)b * L_ * L_;
#pragma unroll
  for (int mi = 0; mi < 4; ++mi) {
#pragma unroll
    for (int ni = 0; ni < 4; ++ni) {
      int col = tn * 128 + wc * 64 + ni * 16 + l15;
      float mr = mrp[col];
#pragma unroll
      for (int r = 0; r < 4; ++r) {
        int row = tm * 128 + wr * 64 + mi * 16 + l4 * 4 + r;
        obase[(size_t)row * L_ + col] = acc[mi][ni][r] * mlp[row] * mr;
      }
    }
  }
}

// ---------- K3: in-place row softmax over 512, then re-mask ----------
__global__ __launch_bounds__(256) void softmax_kernel(float* __restrict__ out,
                                                      const float* __restrict__ mask_lt,
                                                      const float* __restrict__ mask_rt) {
  int lane = threadIdx.x & 63, wave = threadIdx.x >> 6;
  int row = (int)blockIdx.x * 4 + wave;  // 0..32767
  int b = row >> 9;
  float* p = out + (size_t)row * L_;
  float4 v0 = *(const float4*)(p + lane * 8);
  float4 v1 = *(const float4*)(p + lane * 8 + 4);
  float m = fmaxf(fmaxf(fmaxf(v0.x, v0.y), fmaxf(v0.z, v0.w)),
                  fmaxf(fmaxf(v1.x, v1.y), fmaxf(v1.z, v1.w)));
#pragma unroll
  for (int off = 32; off; off >>= 1) m = fmaxf(m, __shfl_xor(m, off));
  float e0 = __expf(v0.x - m), e1 = __expf(v0.y - m), e2 = __expf(v0.z - m), e3 = __expf(v0.w - m);
  float e4 = __expf(v1.x - m), e5 = __expf(v1.y - m), e6 = __expf(v1.z - m), e7 = __expf(v1.w - m);
  float s = ((e0 + e1) + (e2 + e3)) + ((e4 + e5) + (e6 + e7));
#pragma unroll
  for (int off = 32; off; off >>= 1) s += __shfl_xor(s, off);
  float sc = (1.0f / s) * mask_lt[row];
  const float* mrp = mask_rt + (b << 9) + lane * 8;
  float4 mr0 = *(const float4*)mrp;
  float4 mr1 = *(const float4*)(mrp + 4);
  float4 o0 = make_float4(e0 * sc * mr0.x, e1 * sc * mr0.y, e2 * sc * mr0.z, e3 * sc * mr0.w);
  float4 o1 = make_float4(e4 * sc * mr1.x, e5 * sc * mr1.y, e6 * sc * mr1.z, e7 * sc * mr1.w);
  *(float4*)(p + lane * 8) = o0;
  *(float4*)(p + lane * 8 + 4) = o1;
}

extern "C" void kernel_launch(void* const* d_in, const int* in_sizes, int n_in,
                              void* d_out, int out_size, void* d_ws, size_t ws_size,
                              hipStream_t stream) {
  const float* reps_lt = (const float*)d_in[0];
  const float* reps_rt = (const float*)d_in[1];
  const float* mask_lt = (const float*)d_in[2];
  const float* mask_rt = (const float*)d_in[3];
  const float* attn_w1 = (const float*)d_in[4];
  const float* diag    = (const float*)d_in[5];
  float* out = (float*)d_out;

  unsigned short* wt  = (unsigned short*)d_ws;          // 2 MB
  unsigned short* pb  = wt + (size_t)H_ * A_;           // 128 MB
  unsigned short* xb  = pb + (size_t)B_ * L_ * A_ * 2;  // 128 MB
  unsigned short* plt = pb;
  unsigned short* prt = pb + (size_t)B_ * L_ * A_;

  hipLaunchKernelGGL(wtrans_kernel, dim3(1024), dim3(256), 0, stream, attn_w1, wt);
  hipLaunchKernelGGL(cvt_kernel, dim3(8192), dim3(256), 0, stream,
                     reps_lt, reps_rt, xb);
  hipLaunchKernelGGL(proj8_kernel, dim3(1024), dim3(512), 0, stream,
                     xb, wt, diag, pb);
  hipLaunchKernelGGL(score_kernel, dim3(1024), dim3(256), 0, stream,
                     plt, prt, mask_lt, mask_rt, out);
  hipLaunchKernelGGL(softmax_kernel, dim3(8192), dim3(256), 0, stream,
                     out, mask_lt, mask_rt);
}